// Round 12
// baseline (1457.588 us; speedup 1.0000x reference)
//
#include <hip/hip_runtime.h>

// FeatureTokenizer — R12 DIAGNOSTIC: R11 main (unchanged, 192.7us) + a pure-
// store scatter probe now using `sc1 nt` to re-measure the store ceiling
// under the new policy. R8's identical probe WITHOUT sc1 nt measured 5.19
// TB/s; the rocclr fill does 6.5. If sc1-nt-probe ~6.5 -> ~13% left (read
// side); if ~5.7 -> R11 is at the HIP streaming-store roofline.

typedef float fx4 __attribute__((ext_vector_type(4)));

constexpr int kC = 128;
constexpr int kH4 = 32;                        // fx4 per (b,c) row
constexpr int kTotal4 = 1 << 26;               // 67,108,864 fx4 outputs
constexpr int kBlock = 256;
constexpr int kGrid = 2048;
constexpr int kStride4 = kGrid * kBlock;       // 524288 fx4
constexpr int kIters = kTotal4 / kStride4;     // 128 (exact)
constexpr int kRcStep = kStride4 / kH4;        // 16384 rows (== 0 mod kC)

__global__ __launch_bounds__(kBlock) void FeatureTokenizer_69664369541889_kernel(
    const float* __restrict__ x,      // (B, C)
    const float* __restrict__ m,      // (B, C)
    const float* __restrict__ W,      // (C, H)
    const float* __restrict__ bias,   // (C, H)
    const float* __restrict__ me,     // (1, H)
    float* __restrict__ out)          // (B, C, H)
{
    const fx4* __restrict__ W4  = reinterpret_cast<const fx4*>(W);
    const fx4* __restrict__ b4  = reinterpret_cast<const fx4*>(bias);
    const fx4* __restrict__ me4 = reinterpret_cast<const fx4*>(me);
    fx4* __restrict__ out4      = reinterpret_cast<fx4*>(out);

    const int idx0 = blockIdx.x * kBlock + threadIdx.x;   // [0, 524288)
    const int h4   = idx0 & (kH4 - 1);
    int rc         = idx0 >> 5;                           // [0, 16384)
    const int cc   = rc & (kC - 1);                       // fixed per thread

    const fx4 w  = W4[cc * kH4 + h4];
    const fx4 bb = b4[cc * kH4 + h4];
    const fx4 e  = me4[h4];

    int oidx = idx0;
#pragma unroll 8
    for (int it = 0; it < kIters; ++it) {
        const float xv = x[rc];
        const float mv = m[rc];
        const float om = 1.0f - mv;

        fx4 o;
        o.x = fmaf(fmaf(xv, w.x, bb.x), om, e.x * mv);
        o.y = fmaf(fmaf(xv, w.y, bb.y), om, e.y * mv);
        o.z = fmaf(fmaf(xv, w.z, bb.z), om, e.z * mv);
        o.w = fmaf(fmaf(xv, w.w, bb.w), om, e.w * mv);

        fx4* p = &out4[oidx];
        asm volatile("global_store_dwordx4 %0, %1, off sc1 nt"
                     :: "v"(p), "v"(o));

        rc   += kRcStep;
        oidx += kStride4;
    }
}

// Probe: pure-store scatter fill into d_ws with sc1 nt (R8 geometry).
__global__ __launch_bounds__(kBlock) void ws_scatter_fill_nt_probe(
    fx4* __restrict__ ws, long long n4)
{
    fx4 v;
    v.x = 1.0f; v.y = 2.0f; v.z = 3.0f; v.w = 4.0f;
    const long long t0 = (long long)blockIdx.x * kBlock + threadIdx.x;
    for (int pass = 0; pass < 2; ++pass) {
        for (long long idx = t0; idx < n4; idx += (long long)kStride4) {
            fx4* p = &ws[idx];
            asm volatile("global_store_dwordx4 %0, %1, off sc1 nt"
                         :: "v"(p), "v"(v));
        }
    }
}

extern "C" void kernel_launch(void* const* d_in, const int* in_sizes, int n_in,
                              void* d_out, int out_size, void* d_ws, size_t ws_size,
                              hipStream_t stream) {
    const float* x    = (const float*)d_in[0];  // x_numerical (B, C)
    const float* m    = (const float*)d_in[1];  // mask (B, C)
    const float* W    = (const float*)d_in[2];  // W (C, H)
    const float* bias = (const float*)d_in[3];  // b (C, H)
    const float* me   = (const float*)d_in[4];  // mask_embedding (1, H)
    float* out        = (float*)d_out;

    FeatureTokenizer_69664369541889_kernel<<<kGrid, kBlock, 0, stream>>>(
        x, m, W, bias, me, out);

    long long n4 = (long long)(ws_size / 16);
    const long long cap = 3LL * (long long)kTotal4;   // 3.22 GB of fx4
    if (n4 > cap) n4 = cap;
    if (n4 > 0) {
        ws_scatter_fill_nt_probe<<<kGrid, kBlock, 0, stream>>>((fx4*)d_ws, n4);
    }
}